// Round 2
// baseline (3760.161 us; speedup 1.0000x reference)
//
#include <hip/hip_runtime.h>
#include <hip/hip_fp16.h>

#define B_   16
#define T_   4096
#define DIN  256
#define H_   128
#define G3   384   // 3*H

typedef _Float16 half2_t __attribute__((ext_vector_type(2)));

__device__ __forceinline__ float fdot2(unsigned int a, unsigned int b, float c) {
#if __has_builtin(__builtin_amdgcn_fdot2)
  return __builtin_amdgcn_fdot2(__builtin_bit_cast(half2_t, a),
                                __builtin_bit_cast(half2_t, b), c, false);
#else
  const __half2 ha = __builtin_bit_cast(__half2, a);
  const __half2 hb = __builtin_bit_cast(__half2, b);
  return c + __half2float(__low2half(ha)) * __half2float(__low2half(hb))
           + __half2float(__high2half(ha)) * __half2float(__high2half(hb));
#endif
}

__device__ __forceinline__ unsigned int pack2(float x, float y) {
  __half2 h = __floats2half2_rn(x, y);
  return __builtin_bit_cast(unsigned int, h);
}

__device__ __forceinline__ float fsigmoid(float x) {
  return 1.f / (1.f + __expf(-x));
}
__device__ __forceinline__ float ftanh(float x) {
  return 2.f / (1.f + __expf(-2.f * x)) - 1.f;
}

// Workgroup barrier that drains ONLY lgkmcnt (LDS) — leaves global loads and
// stores in flight across the barrier (unlike __syncthreads' vmcnt(0) drain).
// sched_barrier(0) fences prevent the compiler hoisting ds ops across it
// (rule: s_barrier intrinsic alone is not a code-motion fence).
__device__ __forceinline__ void barrier_lds() {
  __builtin_amdgcn_sched_barrier(0);
  asm volatile("s_waitcnt lgkmcnt(0)" ::: "memory");
  __builtin_amdgcn_s_barrier();
  __builtin_amdgcn_sched_barrier(0);
}

// Single-wave LDS fence: ds ops from one wave complete in order; we only need
// the write data landed (lgkmcnt) + no compiler reordering.
__device__ __forceinline__ void wave_lds_fence() {
  __builtin_amdgcn_sched_barrier(0);
  asm volatile("s_waitcnt lgkmcnt(0)" ::: "memory");
  __builtin_amdgcn_sched_barrier(0);
}

// ---------------------------------------------------------------------------
// Kernel 1: gi[r, j] = f16( b_ih[j] + dot(x[r, :], w_ih[j, :]) )
// ---------------------------------------------------------------------------
__global__ __launch_bounds__(384, 1) void gi_gemm(
    const float* __restrict__ x, const float* __restrict__ w_ih,
    const float* __restrict__ b_ih, __half* __restrict__ gi) {
  const int j = threadIdx.x;             // 0..383 : output gate-row
  const int rbase = blockIdx.x * 128;    // 128 x-rows per block

  unsigned int wreg[128];                // 256 halves = w_ih row j
  const float* wrow = w_ih + (size_t)j * DIN;
#pragma unroll
  for (int k = 0; k < 128; ++k) {
    float2 w2 = reinterpret_cast<const float2*>(wrow)[k];
    wreg[k] = pack2(w2.x, w2.y);
  }
  const float bias = b_ih[j];

  __shared__ alignas(16) unsigned int xs[16 * 128];  // 16 rows x 256 halves

  for (int c = 0; c < 8; ++c) {          // 8 chunks of 16 rows
    barrier_lds();                       // protect xs vs previous chunk reads
    const int row0 = rbase + c * 16;
    for (int i = j; i < 16 * 128; i += 384) {
      const int r = i >> 7, col = i & 127;
      float2 v = reinterpret_cast<const float2*>(x + (size_t)(row0 + r) * DIN)[col];
      xs[i] = pack2(v.x, v.y);
    }
    barrier_lds();
    for (int r = 0; r < 16; ++r) {
      float a0 = 0.f, a1 = 0.f, a2 = 0.f, a3 = 0.f;
      const uint4* hp = reinterpret_cast<const uint4*>(xs + r * 128);
#pragma unroll
      for (int k = 0; k < 32; ++k) {
        uint4 hv = hp[k];                // uniform addr -> LDS broadcast
        a0 = fdot2(wreg[4 * k + 0], hv.x, a0);
        a1 = fdot2(wreg[4 * k + 1], hv.y, a1);
        a2 = fdot2(wreg[4 * k + 2], hv.z, a2);
        a3 = fdot2(wreg[4 * k + 3], hv.w, a3);
      }
      const float acc = bias + ((a0 + a1) + (a2 + a3));
      gi[(size_t)(row0 + r) * G3 + j] = __float2half(acc);
    }
  }
}

// ---------------------------------------------------------------------------
// Kernel 2: sequential GRU scan. One block per batch element (16 blocks).
// Thread j (0..383) owns w_hh row j in registers; h broadcast via LDS (f16).
// Barriers drain lgkmcnt only; gi prefetch has ~2-step load-to-use slack via
// statically double-buffered registers (t-loop unrolled by 2, rule #20).
// ---------------------------------------------------------------------------
__global__ __launch_bounds__(384, 1) void gru_scan(
    const __half* __restrict__ gi, const float* __restrict__ w_hh,
    const float* __restrict__ b_hh, float* __restrict__ out) {
  const int b = blockIdx.x;
  const int j = threadIdx.x;

  unsigned int wreg[64];                 // 128 halves = w_hh row j
  const float* wrow = w_hh + (size_t)j * H_;
#pragma unroll
  for (int k = 0; k < 64; ++k) {
    float2 w2 = reinterpret_cast<const float2*>(wrow)[k];
    wreg[k] = pack2(w2.x, w2.y);
  }
  const float bias = b_hh[j];

  __shared__ alignas(16) unsigned int h16[64];  // 128 halves: current h
  __shared__ float gh[G3];

  const __half* gp = gi + (size_t)b * T_ * G3;
  float* op = out + (size_t)b * T_ * H_;

  if (j < 64) h16[j] = 0u;               // h0 = 0

  float ga0 = 0.f, gz0 = 0.f, gn0 = 0.f, ga1 = 0.f, gz1 = 0.f, gn1 = 0.f;
  float hprev = 0.f;
  if (j < H_) {
    ga0 = __half2float(gp[j]);
    gz0 = __half2float(gp[j + 128]);
    gn0 = __half2float(gp[j + 256]);
    ga1 = __half2float(gp[G3 + j]);
    gz1 = __half2float(gp[G3 + j + 128]);
    gn1 = __half2float(gp[G3 + j + 256]);
  }
  barrier_lds();

  // One GRU step at time TT consuming prefetch regs (GA,GZ,GN); refills the
  // SAME named regs for TT+2 (consumed 2 steps later -> ~2 steps of slack,
  // vmcnt wait lands on data loaded ~1000+ cycles earlier).
#define GRU_STEP(TT, GA, GZ, GN)                                           \
  {                                                                        \
    float a0 = 0.f, a1 = 0.f, a2 = 0.f, a3 = 0.f;                          \
    const uint4* hp = reinterpret_cast<const uint4*>(h16);                 \
    _Pragma("unroll")                                                      \
    for (int k = 0; k < 16; ++k) {                                         \
      uint4 hv = hp[k];                 /* uniform addr -> broadcast */    \
      a0 = fdot2(wreg[4 * k + 0], hv.x, a0);                               \
      a1 = fdot2(wreg[4 * k + 1], hv.y, a1);                               \
      a2 = fdot2(wreg[4 * k + 2], hv.z, a2);                               \
      a3 = fdot2(wreg[4 * k + 3], hv.w, a3);                               \
    }                                                                      \
    const float ghj = bias + ((a0 + a1) + (a2 + a3));                      \
    gh[j] = ghj;                                                           \
    barrier_lds();                                                         \
    if (j < H_) {                                                          \
      const float r = fsigmoid(GA + ghj);  /* own row IS the r-term */     \
      const float z = fsigmoid(GZ + gh[j + 128]);                          \
      const float n = ftanh(GN + r * gh[j + 256]);                         \
      const float h = fmaf(z, hprev - n, n); /* (1-z)n + z*hprev */        \
      op[(size_t)(TT) * H_ + j] = h;                                       \
      hprev = h;                                                           \
      reinterpret_cast<__half*>(h16)[j] = __float2half(h);                 \
      if ((TT) + 2 < T_) {                                                 \
        const __half* g2 = gp + (size_t)((TT) + 2) * G3;                   \
        GA = __half2float(g2[j]);                                          \
        GZ = __half2float(g2[j + 128]);                                    \
        GN = __half2float(g2[j + 256]);                                    \
      }                                                                    \
    }                                                                      \
    barrier_lds();                                                         \
  }

  for (int t = 0; t < T_; t += 2) {
    GRU_STEP(t,     ga0, gz0, gn0)
    GRU_STEP(t + 1, ga1, gz1, gn1)
  }
#undef GRU_STEP
}

// ---------------------------------------------------------------------------
// Kernel 3: y = h @ w_proj.T + b_proj, then LayerNorm. In-place on io.
// One wave per block; 64 rows per block; zero-cost wave fences (no s_barrier).
// ---------------------------------------------------------------------------
#define PROJ_ROWS 64
__global__ __launch_bounds__(64, 1) void proj_ln(
    float* __restrict__ io, const float* __restrict__ w_proj,
    const float* __restrict__ b_proj, const float* __restrict__ gamma,
    const float* __restrict__ beta) {
  const int lane = threadIdx.x;
  const int row0 = blockIdx.x * PROJ_ROWS;
  const int jA = lane, jB = lane + 64;

  unsigned int wa[64], wb[64];
#pragma unroll
  for (int k = 0; k < 64; ++k) {
    float2 v = reinterpret_cast<const float2*>(w_proj + (size_t)jA * H_)[k];
    wa[k] = pack2(v.x, v.y);
  }
#pragma unroll
  for (int k = 0; k < 64; ++k) {
    float2 v = reinterpret_cast<const float2*>(w_proj + (size_t)jB * H_)[k];
    wb[k] = pack2(v.x, v.y);
  }
  const float bA = b_proj[jA], bB = b_proj[jB];
  const float gmA = gamma[jA], gmB = gamma[jB];
  const float btA = beta[jA], btB = beta[jB];

  __shared__ alignas(16) unsigned int hbuf[64];  // 128 halves: one h row

  for (int r = 0; r < PROJ_ROWS; ++r) {
    float* rowp = io + (size_t)(row0 + r) * H_;
    float2 v = reinterpret_cast<float2*>(rowp)[lane];
    hbuf[lane] = pack2(v.x, v.y);
    wave_lds_fence();                    // write visible to whole wave

    float aA = bA, aB = bB;
    const uint4* hp = reinterpret_cast<const uint4*>(hbuf);
#pragma unroll
    for (int k = 0; k < 16; ++k) {
      uint4 hv = hp[k];
      aA = fdot2(wa[4 * k + 0], hv.x, aA);
      aA = fdot2(wa[4 * k + 1], hv.y, aA);
      aA = fdot2(wa[4 * k + 2], hv.z, aA);
      aA = fdot2(wa[4 * k + 3], hv.w, aA);
      aB = fdot2(wb[4 * k + 0], hv.x, aB);
      aB = fdot2(wb[4 * k + 1], hv.y, aB);
      aB = fdot2(wb[4 * k + 2], hv.z, aB);
      aB = fdot2(wb[4 * k + 3], hv.w, aB);
    }

    float s = aA + aB;
    float q = aA * aA + aB * aB;
#pragma unroll
    for (int m = 1; m < 64; m <<= 1) {
      s += __shfl_xor(s, m, 64);
      q += __shfl_xor(q, m, 64);
    }
    const float mu = s * (1.f / 128.f);
    const float var = q * (1.f / 128.f) - mu * mu;
    const float rs = rsqrtf(var + 1e-5f);
    rowp[lane]      = (aA - mu) * rs * gmA + btA;
    rowp[lane + 64] = (aB - mu) * rs * gmB + btB;
    wave_lds_fence();                    // reads done before next overwrite
  }
}

// ---------------------------------------------------------------------------
extern "C" void kernel_launch(void* const* d_in, const int* in_sizes, int n_in,
                              void* d_out, int out_size, void* d_ws, size_t ws_size,
                              hipStream_t stream) {
  const float* x      = (const float*)d_in[0];
  const float* w_ih   = (const float*)d_in[1];
  const float* w_hh   = (const float*)d_in[2];
  const float* b_ih   = (const float*)d_in[3];
  const float* b_hh   = (const float*)d_in[4];
  const float* w_proj = (const float*)d_in[5];
  const float* b_proj = (const float*)d_in[6];
  const float* gamma  = (const float*)d_in[7];
  const float* beta   = (const float*)d_in[8];

  float* out = (float*)d_out;
  __half* gi = (__half*)d_ws;            // 65536*384 f16 = 48 MB scratch

  gi_gemm<<<512, 384, 0, stream>>>(x, w_ih, b_ih, gi);
  gru_scan<<<B_, 384, 0, stream>>>(gi, w_hh, b_hh, out);
  proj_ln<<<(B_ * T_) / PROJ_ROWS, 64, 0, stream>>>(out, w_proj, b_proj, gamma, beta);
}

// Round 3
// 3191.966 us; speedup vs baseline: 1.1780x; 1.1780x over previous
//
#include <hip/hip_runtime.h>
#include <hip/hip_fp16.h>

#define B_   16
#define T_   4096
#define DIN  256
#define H_   128
#define G3   384   // 3*H

typedef _Float16 half2_t __attribute__((ext_vector_type(2)));

__device__ __forceinline__ float fdot2(unsigned int a, unsigned int b, float c) {
#if __has_builtin(__builtin_amdgcn_fdot2)
  return __builtin_amdgcn_fdot2(__builtin_bit_cast(half2_t, a),
                                __builtin_bit_cast(half2_t, b), c, false);
#else
  const __half2 ha = __builtin_bit_cast(__half2, a);
  const __half2 hb = __builtin_bit_cast(__half2, b);
  return c + __half2float(__low2half(ha)) * __half2float(__low2half(hb))
           + __half2float(__high2half(ha)) * __half2float(__high2half(hb));
#endif
}

__device__ __forceinline__ unsigned int pack2(float x, float y) {
  __half2 h = __floats2half2_rn(x, y);
  return __builtin_bit_cast(unsigned int, h);
}

__device__ __forceinline__ float fsigmoid(float x) {
  return 1.f / (1.f + __expf(-x));
}
__device__ __forceinline__ float ftanh(float x) {
  return 2.f / (1.f + __expf(-2.f * x)) - 1.f;
}

// lgkmcnt-only barrier (no vmcnt drain, no sched_barrier pins).
__device__ __forceinline__ void scan_barrier() {
  asm volatile("s_waitcnt lgkmcnt(0)" ::: "memory");
  __builtin_amdgcn_s_barrier();
  asm volatile("" ::: "memory");
}

__device__ __forceinline__ void barrier_lds() {
  __builtin_amdgcn_sched_barrier(0);
  asm volatile("s_waitcnt lgkmcnt(0)" ::: "memory");
  __builtin_amdgcn_s_barrier();
  __builtin_amdgcn_sched_barrier(0);
}

__device__ __forceinline__ void wave_lds_fence() {
  __builtin_amdgcn_sched_barrier(0);
  asm volatile("s_waitcnt lgkmcnt(0)" ::: "memory");
  __builtin_amdgcn_sched_barrier(0);
}

// ---------------------------------------------------------------------------
// Kernel 1: gi[r, j] = f16( b_ih[j] + dot(x[r, :], w_ih[j, :]) )
// ---------------------------------------------------------------------------
__global__ __launch_bounds__(384, 1) void gi_gemm(
    const float* __restrict__ x, const float* __restrict__ w_ih,
    const float* __restrict__ b_ih, __half* __restrict__ gi) {
  const int j = threadIdx.x;             // 0..383 : output gate-row
  const int rbase = blockIdx.x * 128;    // 128 x-rows per block

  unsigned int wreg[128];                // 256 halves = w_ih row j
  const float* wrow = w_ih + (size_t)j * DIN;
#pragma unroll
  for (int k = 0; k < 128; ++k) {
    float2 w2 = reinterpret_cast<const float2*>(wrow)[k];
    wreg[k] = pack2(w2.x, w2.y);
  }
  const float bias = b_ih[j];

  __shared__ alignas(16) unsigned int xs[16 * 128];  // 16 rows x 256 halves

  for (int c = 0; c < 8; ++c) {          // 8 chunks of 16 rows
    barrier_lds();                       // protect xs vs previous chunk reads
    const int row0 = rbase + c * 16;
    for (int i = j; i < 16 * 128; i += 384) {
      const int r = i >> 7, col = i & 127;
      float2 v = reinterpret_cast<const float2*>(x + (size_t)(row0 + r) * DIN)[col];
      xs[i] = pack2(v.x, v.y);
    }
    barrier_lds();
    for (int r = 0; r < 16; ++r) {
      float a0 = 0.f, a1 = 0.f, a2 = 0.f, a3 = 0.f;
      const uint4* hp = reinterpret_cast<const uint4*>(xs + r * 128);
#pragma unroll
      for (int k = 0; k < 32; ++k) {
        uint4 hv = hp[k];                // uniform addr -> LDS broadcast
        a0 = fdot2(wreg[4 * k + 0], hv.x, a0);
        a1 = fdot2(wreg[4 * k + 1], hv.y, a1);
        a2 = fdot2(wreg[4 * k + 2], hv.z, a2);
        a3 = fdot2(wreg[4 * k + 3], hv.w, a3);
      }
      const float acc = bias + ((a0 + a1) + (a2 + a3));
      gi[(size_t)(row0 + r) * G3 + j] = __float2half(acc);
    }
  }
}

// ---------------------------------------------------------------------------
// Kernel 2: sequential GRU scan. One block of 128 threads (2 waves) per batch
// element. Thread j owns ALL THREE w_hh rows of its column (r_j, z_j, n_j) in
// registers -> entire gate computation is register-local, no gh exchange.
// Only cross-thread dependency: h broadcast (double-buffered f16 in LDS) ->
// ONE barrier per step.
// ---------------------------------------------------------------------------
__global__ __launch_bounds__(128, 1) void gru_scan(
    const __half* __restrict__ gi, const float* __restrict__ w_hh,
    const float* __restrict__ b_hh, float* __restrict__ out) {
  const int b = blockIdx.x;
  const int j = threadIdx.x;             // column 0..127

  unsigned int wr[64], wz[64], wn[64];   // rows j, j+128, j+256 as f16x2
  {
    const float* rr = w_hh + (size_t)j * H_;
    const float* rz = w_hh + (size_t)(j + 128) * H_;
    const float* rn = w_hh + (size_t)(j + 256) * H_;
#pragma unroll
    for (int k = 0; k < 64; ++k) {
      float2 a = reinterpret_cast<const float2*>(rr)[k]; wr[k] = pack2(a.x, a.y);
    }
#pragma unroll
    for (int k = 0; k < 64; ++k) {
      float2 a = reinterpret_cast<const float2*>(rz)[k]; wz[k] = pack2(a.x, a.y);
    }
#pragma unroll
    for (int k = 0; k < 64; ++k) {
      float2 a = reinterpret_cast<const float2*>(rn)[k]; wn[k] = pack2(a.x, a.y);
    }
  }
  const float br = b_hh[j], bz = b_hh[j + 128], bn = b_hh[j + 256];

  // Double-buffered h (f16): removes the WAR hazard between this step's
  // broadcast reads and this step's h writes -> single barrier per step.
  __shared__ alignas(16) unsigned int h16a[64];
  __shared__ alignas(16) unsigned int h16b[64];

  const __half* gp = gi + (size_t)b * T_ * G3;
  float* op = out + (size_t)b * T_ * H_;

  if (j < 64) h16a[j] = 0u;              // h0 = 0 (buffer A = even steps)
  float hprev = 0.f;

  // 2-step-deep gi prefetch, kept as raw __half so the vmcnt wait lands at
  // the float-convert (use site), not at the load.
  __half pa0 = gp[j], pz0 = gp[j + 128], pn0 = gp[j + 256];
  __half pa1 = gp[G3 + j], pz1 = gp[G3 + j + 128], pn1 = gp[G3 + j + 256];
  scan_barrier();

#define GRU_STEP(TT, PA, PZ, PN, RB, WB)                                    \
  {                                                                         \
    const float ga = __half2float(PA);                                      \
    const float gz = __half2float(PZ);                                      \
    const float gn = __half2float(PN);                                      \
    if ((TT) + 2 < T_) {   /* refill same named regs for TT+2 */            \
      const __half* g2 = gp + (size_t)((TT) + 2) * G3;                      \
      PA = g2[j]; PZ = g2[j + 128]; PN = g2[j + 256];                       \
    }                                                                       \
    float r0 = 0.f, r1 = 0.f, r2 = 0.f, r3 = 0.f;                           \
    float z0 = 0.f, z1 = 0.f, z2 = 0.f, z3 = 0.f;                           \
    float n0 = 0.f, n1 = 0.f, n2 = 0.f, n3 = 0.f;                           \
    const uint4* hp = reinterpret_cast<const uint4*>(RB);                   \
    _Pragma("unroll")                                                       \
    for (int k = 0; k < 16; ++k) {                                          \
      const uint4 hv = hp[k];           /* uniform addr -> broadcast */     \
      r0 = fdot2(wr[4 * k + 0], hv.x, r0);                                  \
      r1 = fdot2(wr[4 * k + 1], hv.y, r1);                                  \
      r2 = fdot2(wr[4 * k + 2], hv.z, r2);                                  \
      r3 = fdot2(wr[4 * k + 3], hv.w, r3);                                  \
      z0 = fdot2(wz[4 * k + 0], hv.x, z0);                                  \
      z1 = fdot2(wz[4 * k + 1], hv.y, z1);                                  \
      z2 = fdot2(wz[4 * k + 2], hv.z, z2);                                  \
      z3 = fdot2(wz[4 * k + 3], hv.w, z3);                                  \
      n0 = fdot2(wn[4 * k + 0], hv.x, n0);                                  \
      n1 = fdot2(wn[4 * k + 1], hv.y, n1);                                  \
      n2 = fdot2(wn[4 * k + 2], hv.z, n2);                                  \
      n3 = fdot2(wn[4 * k + 3], hv.w, n3);                                  \
    }                                                                       \
    const float dr = br + ((r0 + r1) + (r2 + r3));                          \
    const float dz = bz + ((z0 + z1) + (z2 + z3));                          \
    const float dn = bn + ((n0 + n1) + (n2 + n3));                          \
    const float rg = fsigmoid(ga + dr);                                     \
    const float zg = fsigmoid(gz + dz);                                     \
    const float ng = ftanh(gn + rg * dn);                                   \
    const float h  = fmaf(zg, hprev - ng, ng);                              \
    op[(size_t)(TT) * H_ + j] = h;                                          \
    hprev = h;                                                              \
    reinterpret_cast<__half*>(WB)[j] = __float2half(h);                     \
    scan_barrier();                                                         \
  }

  for (int t = 0; t < T_; t += 2) {
    GRU_STEP(t,     pa0, pz0, pn0, h16a, h16b)
    GRU_STEP(t + 1, pa1, pz1, pn1, h16b, h16a)
  }
#undef GRU_STEP
}

// ---------------------------------------------------------------------------
// Kernel 3: y = h @ w_proj.T + b_proj, then LayerNorm. In-place on io.
// ---------------------------------------------------------------------------
#define PROJ_ROWS 64
__global__ __launch_bounds__(64, 1) void proj_ln(
    float* __restrict__ io, const float* __restrict__ w_proj,
    const float* __restrict__ b_proj, const float* __restrict__ gamma,
    const float* __restrict__ beta) {
  const int lane = threadIdx.x;
  const int row0 = blockIdx.x * PROJ_ROWS;
  const int jA = lane, jB = lane + 64;

  unsigned int wa[64], wb[64];
#pragma unroll
  for (int k = 0; k < 64; ++k) {
    float2 v = reinterpret_cast<const float2*>(w_proj + (size_t)jA * H_)[k];
    wa[k] = pack2(v.x, v.y);
  }
#pragma unroll
  for (int k = 0; k < 64; ++k) {
    float2 v = reinterpret_cast<const float2*>(w_proj + (size_t)jB * H_)[k];
    wb[k] = pack2(v.x, v.y);
  }
  const float bA = b_proj[jA], bB = b_proj[jB];
  const float gmA = gamma[jA], gmB = gamma[jB];
  const float btA = beta[jA], btB = beta[jB];

  __shared__ alignas(16) unsigned int hbuf[64];  // 128 halves: one h row

  for (int r = 0; r < PROJ_ROWS; ++r) {
    float* rowp = io + (size_t)(row0 + r) * H_;
    float2 v = reinterpret_cast<float2*>(rowp)[lane];
    hbuf[lane] = pack2(v.x, v.y);
    wave_lds_fence();                    // write visible to whole wave

    float aA = bA, aB = bB;
    const uint4* hp = reinterpret_cast<const uint4*>(hbuf);
#pragma unroll
    for (int k = 0; k < 16; ++k) {
      uint4 hv = hp[k];
      aA = fdot2(wa[4 * k + 0], hv.x, aA);
      aA = fdot2(wa[4 * k + 1], hv.y, aA);
      aA = fdot2(wa[4 * k + 2], hv.z, aA);
      aA = fdot2(wa[4 * k + 3], hv.w, aA);
      aB = fdot2(wb[4 * k + 0], hv.x, aB);
      aB = fdot2(wb[4 * k + 1], hv.y, aB);
      aB = fdot2(wb[4 * k + 2], hv.z, aB);
      aB = fdot2(wb[4 * k + 3], hv.w, aB);
    }

    float s = aA + aB;
    float q = aA * aA + aB * aB;
#pragma unroll
    for (int m = 1; m < 64; m <<= 1) {
      s += __shfl_xor(s, m, 64);
      q += __shfl_xor(q, m, 64);
    }
    const float mu = s * (1.f / 128.f);
    const float var = q * (1.f / 128.f) - mu * mu;
    const float rs = rsqrtf(var + 1e-5f);
    rowp[lane]      = (aA - mu) * rs * gmA + btA;
    rowp[lane + 64] = (aB - mu) * rs * gmB + btB;
    wave_lds_fence();                    // reads done before next overwrite
  }
}

// ---------------------------------------------------------------------------
extern "C" void kernel_launch(void* const* d_in, const int* in_sizes, int n_in,
                              void* d_out, int out_size, void* d_ws, size_t ws_size,
                              hipStream_t stream) {
  const float* x      = (const float*)d_in[0];
  const float* w_ih   = (const float*)d_in[1];
  const float* w_hh   = (const float*)d_in[2];
  const float* b_ih   = (const float*)d_in[3];
  const float* b_hh   = (const float*)d_in[4];
  const float* w_proj = (const float*)d_in[5];
  const float* b_proj = (const float*)d_in[6];
  const float* gamma  = (const float*)d_in[7];
  const float* beta   = (const float*)d_in[8];

  float* out = (float*)d_out;
  __half* gi = (__half*)d_ws;            // 65536*384 f16 = 48 MB scratch

  gi_gemm<<<512, 384, 0, stream>>>(x, w_ih, b_ih, gi);
  gru_scan<<<B_, 128, 0, stream>>>(gi, w_hh, b_hh, out);
  proj_ln<<<(B_ * T_) / PROJ_ROWS, 64, 0, stream>>>(out, w_proj, b_proj, gamma, beta);
}